// Round 3
// baseline (2996.562 us; speedup 1.0000x reference)
//
#include <hip/hip_runtime.h>
#include <hip/hip_bf16.h>

// Problem constants (PolyhedronModel CGConv): fixed sizes per reference.
#define NN 50000      // nodes
#define EE 800000     // edges
#define CC 64         // node channels
#define DE 32         // edge feature dim
#define KD 160        // 2*CC + DE
#define GG 512        // graphs
#define EPB 64        // edges per block
#define ZS 164        // z row stride in dwords: 164*4=656 bytes, 16B-aligned rows

__device__ __forceinline__ float sigmoidf_(float v) {
  return __fdividef(1.f, 1.f + __expf(-v));
}
// jax.nn.softplus(x) = max(x,0) + log1p(exp(-|x|))
__device__ __forceinline__ float softplusf_(float v) {
  return fmaxf(v, 0.f) + __logf(1.f + __expf(-fabsf(v)));
}

// Edge kernel: z = [x[dst] | x[src] | edge_attr]  (160)
// msg = sigmoid(z@Wf + bf) * softplus(z@Ws + bs)  (64)
// atomicAdd into agg[dst].
// Layout: 64 edges staged per block in LDS; 4 waves x 16 channels; lane = edge.
// Weights are loaded at wave-uniform addresses as float4 so the worst case is
// 32 broadcast VMEM ops per k-chunk (vs 256 VALU cycles) — never issue-bound.
__global__ __launch_bounds__(256) void edge_kernel(
    const float* __restrict__ x, const int* __restrict__ ei,
    const float* __restrict__ ea,
    const float* __restrict__ Wf, const float* __restrict__ bfv,
    const float* __restrict__ Ws, const float* __restrict__ bsv,
    float* __restrict__ agg)
{
  __shared__ float z[EPB * ZS];
  __shared__ int sdst[EPB];
  __shared__ int ssrc[EPB];
  const int t  = threadIdx.x;
  const int e0 = blockIdx.x * EPB;

  if (t < EPB)            sdst[t]       = ei[EE + e0 + t];   // edge_index[1] = dst
  else if (t < 2 * EPB)   ssrc[t - EPB] = ei[e0 + t - EPB];  // edge_index[0] = src
  __syncthreads();

  // ---- stage z into LDS (float4, coalesced; rows 16B-aligned) ----
  #pragma unroll
  for (int rep = 0; rep < 4; ++rep) {           // x[dst]: 64 edges * 16 float4
    int idx = rep * 256 + t;
    int e = idx >> 4, kv = idx & 15;
    const float4* s4 = (const float4*)(x + (size_t)sdst[e] * CC);
    *(float4*)&z[e * ZS + kv * 4] = s4[kv];
  }
  #pragma unroll
  for (int rep = 0; rep < 4; ++rep) {           // x[src]
    int idx = rep * 256 + t;
    int e = idx >> 4, kv = idx & 15;
    const float4* s4 = (const float4*)(x + (size_t)ssrc[e] * CC);
    *(float4*)&z[e * ZS + CC + kv * 4] = s4[kv];
  }
  #pragma unroll
  for (int rep = 0; rep < 2; ++rep) {           // edge_attr: 64 edges * 8 float4
    int idx = rep * 256 + t;
    int e = idx >> 3, kv = idx & 7;
    const float4* s4 = (const float4*)(ea + (size_t)(e0 + e) * DE);
    *(float4*)&z[e * ZS + 2 * CC + kv * 4] = s4[kv];
  }
  __syncthreads();

  // ---- compute: wave w handles channels [16w, 16w+16); lane = edge ----
  const int lane = t & 63;
  const int ch0  = __builtin_amdgcn_readfirstlane((t >> 6) * 16); // wave-uniform

  float af[16], as_[16];
  #pragma unroll
  for (int i = 0; i < 16; ++i) { af[i] = bfv[ch0 + i]; as_[i] = bsv[ch0 + i]; }

  const float4* zrow = (const float4*)&z[lane * ZS];
  #pragma unroll 2
  for (int kk = 0; kk < KD / 4; ++kk) {
    float4 zv = zrow[kk];
    // Weight tiles for k in [4kk, 4kk+4), channels [ch0, ch0+16).
    // Uniform addresses, explicit float4: 32 loads per kk vs 128 FMAs.
    #pragma unroll
    for (int r = 0; r < 4; ++r) {
      const float zk = (r == 0) ? zv.x : (r == 1) ? zv.y : (r == 2) ? zv.z : zv.w;
      const float4* wf4 = (const float4*)(Wf + (size_t)(kk * 4 + r) * CC + ch0);
      const float4* ws4 = (const float4*)(Ws + (size_t)(kk * 4 + r) * CC + ch0);
      #pragma unroll
      for (int q = 0; q < 4; ++q) {
        float4 wf = wf4[q];
        float4 ws = ws4[q];
        af[q * 4 + 0]  = fmaf(zk, wf.x, af[q * 4 + 0]);
        af[q * 4 + 1]  = fmaf(zk, wf.y, af[q * 4 + 1]);
        af[q * 4 + 2]  = fmaf(zk, wf.z, af[q * 4 + 2]);
        af[q * 4 + 3]  = fmaf(zk, wf.w, af[q * 4 + 3]);
        as_[q * 4 + 0] = fmaf(zk, ws.x, as_[q * 4 + 0]);
        as_[q * 4 + 1] = fmaf(zk, ws.y, as_[q * 4 + 1]);
        as_[q * 4 + 2] = fmaf(zk, ws.z, as_[q * 4 + 2]);
        as_[q * 4 + 3] = fmaf(zk, ws.w, as_[q * 4 + 3]);
      }
    }
  }

  // ---- epilogue: activations + scatter-add ----
  const int dn = sdst[lane];
  float* arow = agg + (size_t)dn * CC + ch0;
  #pragma unroll
  for (int i = 0; i < 16; ++i) {
    atomicAdd(arow + i, sigmoidf_(af[i]) * softplusf_(as_[i]));
  }
}

// Node kernel: h = sigmoid(x + agg); o = sigmoid(h @ W1 + b1) (6);
// atomicAdd o into pool[batch[n]].
__global__ __launch_bounds__(256) void node_kernel(
    const float* __restrict__ x, const float* __restrict__ agg,
    const int* __restrict__ batch,
    const float* __restrict__ W1, const float* __restrict__ b1,
    float* __restrict__ pool)
{
  int n = blockIdx.x * 256 + threadIdx.x;
  if (n >= NN) return;
  const float4* xr = (const float4*)(x + (size_t)n * CC);
  const float4* ar = (const float4*)(agg + (size_t)n * CC);
  float o[6];
  #pragma unroll
  for (int j = 0; j < 6; ++j) o[j] = b1[j];
  #pragma unroll
  for (int i = 0; i < 16; ++i) {
    float4 a = xr[i];
    float4 b = ar[i];
    float hv0 = sigmoidf_(a.x + b.x);
    float hv1 = sigmoidf_(a.y + b.y);
    float hv2 = sigmoidf_(a.z + b.z);
    float hv3 = sigmoidf_(a.w + b.w);
    const float* w = W1 + (size_t)(i * 4) * 6;
    #pragma unroll
    for (int j = 0; j < 6; ++j) {
      o[j] = fmaf(hv0, w[j],      o[j]);
      o[j] = fmaf(hv1, w[6 + j],  o[j]);
      o[j] = fmaf(hv2, w[12 + j], o[j]);
      o[j] = fmaf(hv3, w[18 + j], o[j]);
    }
  }
  int g = batch[n];
  #pragma unroll
  for (int j = 0; j < 6; ++j) atomicAdd(&pool[g * 6 + j], sigmoidf_(o[j]));
}

// Head: out[g] = relu(pool[g] @ W2 + b2)
__global__ void out_kernel(const float* __restrict__ pool,
                           const float* __restrict__ W2,
                           const float* __restrict__ b2,
                           float* __restrict__ out)
{
  int g = blockIdx.x * 64 + threadIdx.x;
  if (g < GG) {
    float acc = b2[0];
    #pragma unroll
    for (int j = 0; j < 6; ++j) acc = fmaf(pool[g * 6 + j], W2[j], acc);
    out[g] = fmaxf(acc, 0.f);
  }
}

extern "C" void kernel_launch(void* const* d_in, const int* in_sizes, int n_in,
                              void* d_out, int out_size, void* d_ws, size_t ws_size,
                              hipStream_t stream) {
  const float* x     = (const float*)d_in[0];
  const int*   ei    = (const int*)d_in[1];
  const float* ea    = (const float*)d_in[2];
  const int*   batch = (const int*)d_in[3];
  // d_in[4] = num_graphs (scalar) — unused, sizes are fixed
  const float* Wf = (const float*)d_in[5];
  const float* bf = (const float*)d_in[6];
  const float* Ws = (const float*)d_in[7];
  const float* bs = (const float*)d_in[8];
  const float* W1 = (const float*)d_in[9];
  const float* b1 = (const float*)d_in[10];
  const float* W2 = (const float*)d_in[11];
  const float* b2 = (const float*)d_in[12];

  float* agg  = (float*)d_ws;                    // [NN, CC]
  float* pool = agg + (size_t)NN * CC;           // [GG, 6]
  float* out  = (float*)d_out;                   // [GG, 1]

  hipMemsetAsync(agg, 0, (size_t)NN * CC * sizeof(float), stream);
  hipMemsetAsync(pool, 0, (size_t)GG * 6 * sizeof(float), stream);

  edge_kernel<<<EE / EPB, 256, 0, stream>>>(x, ei, ea, Wf, bf, Ws, bs, agg);
  node_kernel<<<(NN + 255) / 256, 256, 0, stream>>>(x, agg, batch, W1, b1, pool);
  out_kernel<<<(GG + 63) / 64, 64, 0, stream>>>(pool, W2, b2, out);
}

// Round 5
// 865.369 us; speedup vs baseline: 3.4628x; 3.4628x over previous
//
#include <hip/hip_runtime.h>
#include <hip/hip_bf16.h>
#include <stdint.h>

// Problem constants (PolyhedronModel CGConv): fixed sizes per reference.
#define NN 50000      // nodes
#define EE 800000     // edges
#define CC 64         // node channels
#define DE 32         // edge feature dim
#define KD 160        // 2*CC + DE
#define GG 512        // graphs
#define EPB 64        // edges per block
#define ZS 164        // z row stride in dwords (16B-aligned rows)
#define SCAN_B 1024
#define NSCAN ((NN + SCAN_B - 1) / SCAN_B)   // 49

__device__ __forceinline__ float sigmoidf_(float v) {
  return __fdividef(1.f, 1.f + __expf(-v));
}
// jax.nn.softplus(x) = max(x,0) + log1p(exp(-|x|))
__device__ __forceinline__ float softplusf_(float v) {
  return fmaxf(v, 0.f) + __logf(1.f + __expf(-fabsf(v)));
}
__device__ __forceinline__ unsigned short f2bf(float f) {   // RNE bf16
  uint32_t u = __float_as_uint(f);
  return (unsigned short)((u + 0x7FFFu + ((u >> 16) & 1u)) >> 16);
}
__device__ __forceinline__ float bf2f(unsigned short h) {
  return __uint_as_float(((uint32_t)h) << 16);
}

// ---------------- CSR build (by dst) ----------------
__global__ void count_kernel(const int* __restrict__ ei, int* __restrict__ deg) {
  int e = blockIdx.x * 256 + threadIdx.x;          // grid exact: EE/256
  atomicAdd(&deg[ei[EE + e]], 1);                  // dst row
}

__global__ __launch_bounds__(SCAN_B) void scan1_kernel(
    const int* __restrict__ deg, int* __restrict__ pos, int* __restrict__ bsum) {
  __shared__ int s[SCAN_B];
  int t = threadIdx.x, i = blockIdx.x * SCAN_B + t;
  s[t] = (i < NN) ? deg[i] : 0;
  __syncthreads();
  for (int off = 1; off < SCAN_B; off <<= 1) {
    int a = (t >= off) ? s[t - off] : 0;
    __syncthreads();
    s[t] += a;
    __syncthreads();
  }
  if (i < NN) pos[i + 1] = s[t];                   // block-local inclusive scan
  if (t == SCAN_B - 1) bsum[blockIdx.x] = s[t];
}

__global__ void scan2_kernel(int* __restrict__ bsum) {
  __shared__ int s[64];
  int t = threadIdx.x;
  s[t] = (t < NSCAN) ? bsum[t] : 0;
  __syncthreads();
  for (int off = 1; off < 64; off <<= 1) {
    int a = (t >= off) ? s[t - off] : 0;
    __syncthreads();
    s[t] += a;
    __syncthreads();
  }
  bsum[t] = (t == 0) ? 0 : s[t - 1];               // exclusive block offsets
}

__global__ __launch_bounds__(SCAN_B) void scan3_kernel(
    int* __restrict__ pos, const int* __restrict__ bsum, int* __restrict__ cursor) {
  int t = threadIdx.x, i = blockIdx.x * SCAN_B + t;
  if (i < NN) {
    int v = pos[i + 1] + bsum[blockIdx.x];
    pos[i + 1] = v;
    if (i + 1 < NN) cursor[i + 1] = v;             // cursor[j] = pos[j]
  }
  if (i == 0) { pos[0] = 0; cursor[0] = 0; }
}

__global__ void fill_kernel(const int* __restrict__ ei,
                            int* __restrict__ cursor, int* __restrict__ eidx) {
  int e = blockIdx.x * 256 + threadIdx.x;
  int d = ei[EE + e];
  int slot = atomicAdd(&cursor[d], 1);
  eidx[slot] = e;
}

// ---------------- Edge kernel: msg = sig(zWf+bf)*softplus(zWs+bs) ----------------
// z = [x[dst] | x[src] | edge_attr] staged in LDS; 4 waves x 16 channels; lane=edge.
// Output: plain streaming stores to msg[e][64] (NO atomics — that was the 2.8ms wall).
template <bool BF16>
__global__ __launch_bounds__(256) void edge_kernel(
    const float* __restrict__ x, const int* __restrict__ ei,
    const float* __restrict__ ea,
    const float* __restrict__ Wf, const float* __restrict__ bfv,
    const float* __restrict__ Ws, const float* __restrict__ bsv,
    void* __restrict__ msg)
{
  __shared__ float z[EPB * ZS];
  __shared__ int sdst[EPB];
  __shared__ int ssrc[EPB];
  const int t  = threadIdx.x;
  const int e0 = blockIdx.x * EPB;

  if (t < EPB)            sdst[t]       = ei[EE + e0 + t];   // dst
  else if (t < 2 * EPB)   ssrc[t - EPB] = ei[e0 + t - EPB];  // src
  __syncthreads();

  #pragma unroll
  for (int rep = 0; rep < 4; ++rep) {           // x[dst]
    int idx = rep * 256 + t;
    int e = idx >> 4, kv = idx & 15;
    const float4* s4 = (const float4*)(x + (size_t)sdst[e] * CC);
    *(float4*)&z[e * ZS + kv * 4] = s4[kv];
  }
  #pragma unroll
  for (int rep = 0; rep < 4; ++rep) {           // x[src]
    int idx = rep * 256 + t;
    int e = idx >> 4, kv = idx & 15;
    const float4* s4 = (const float4*)(x + (size_t)ssrc[e] * CC);
    *(float4*)&z[e * ZS + CC + kv * 4] = s4[kv];
  }
  #pragma unroll
  for (int rep = 0; rep < 2; ++rep) {           // edge_attr
    int idx = rep * 256 + t;
    int e = idx >> 3, kv = idx & 7;
    const float4* s4 = (const float4*)(ea + (size_t)(e0 + e) * DE);
    *(float4*)&z[e * ZS + 2 * CC + kv * 4] = s4[kv];
  }
  __syncthreads();

  const int lane = t & 63;
  const int ch0  = __builtin_amdgcn_readfirstlane((t >> 6) * 16);

  float af[16], as_[16];
  #pragma unroll
  for (int i = 0; i < 16; ++i) { af[i] = bfv[ch0 + i]; as_[i] = bsv[ch0 + i]; }

  const float4* zrow = (const float4*)&z[lane * ZS];
  #pragma unroll 2
  for (int kk = 0; kk < KD / 4; ++kk) {
    float4 zv = zrow[kk];
    #pragma unroll
    for (int r = 0; r < 4; ++r) {
      const float zk = (r == 0) ? zv.x : (r == 1) ? zv.y : (r == 2) ? zv.z : zv.w;
      const float4* wf4 = (const float4*)(Wf + (size_t)(kk * 4 + r) * CC + ch0);
      const float4* ws4 = (const float4*)(Ws + (size_t)(kk * 4 + r) * CC + ch0);
      #pragma unroll
      for (int q = 0; q < 4; ++q) {
        float4 wf = wf4[q];
        float4 ws = ws4[q];
        af[q * 4 + 0]  = fmaf(zk, wf.x, af[q * 4 + 0]);
        af[q * 4 + 1]  = fmaf(zk, wf.y, af[q * 4 + 1]);
        af[q * 4 + 2]  = fmaf(zk, wf.z, af[q * 4 + 2]);
        af[q * 4 + 3]  = fmaf(zk, wf.w, af[q * 4 + 3]);
        as_[q * 4 + 0] = fmaf(zk, ws.x, as_[q * 4 + 0]);
        as_[q * 4 + 1] = fmaf(zk, ws.y, as_[q * 4 + 1]);
        as_[q * 4 + 2] = fmaf(zk, ws.z, as_[q * 4 + 2]);
        as_[q * 4 + 3] = fmaf(zk, ws.w, as_[q * 4 + 3]);
      }
    }
  }

  const size_t eabs = (size_t)(e0 + lane);
  if constexpr (!BF16) {
    float* mrow = (float*)msg + eabs * CC + ch0;
    #pragma unroll
    for (int q = 0; q < 4; ++q) {
      float4 v;
      v.x = sigmoidf_(af[q * 4 + 0]) * softplusf_(as_[q * 4 + 0]);
      v.y = sigmoidf_(af[q * 4 + 1]) * softplusf_(as_[q * 4 + 1]);
      v.z = sigmoidf_(af[q * 4 + 2]) * softplusf_(as_[q * 4 + 2]);
      v.w = sigmoidf_(af[q * 4 + 3]) * softplusf_(as_[q * 4 + 3]);
      *(float4*)&mrow[q * 4] = v;
    }
  } else {
    unsigned short* mrow = (unsigned short*)msg + eabs * CC + ch0;
    #pragma unroll
    for (int q = 0; q < 4; ++q) {
      ushort4 u;
      u.x = f2bf(sigmoidf_(af[q * 4 + 0]) * softplusf_(as_[q * 4 + 0]));
      u.y = f2bf(sigmoidf_(af[q * 4 + 1]) * softplusf_(as_[q * 4 + 1]));
      u.z = f2bf(sigmoidf_(af[q * 4 + 2]) * softplusf_(as_[q * 4 + 2]));
      u.w = f2bf(sigmoidf_(af[q * 4 + 3]) * softplusf_(as_[q * 4 + 3]));
      *(ushort4*)&mrow[q * 4] = u;
    }
  }
}

// ---------------- Fused gather + node head ----------------
// 16 threads per node (thread i owns channels 4i..4i+3). Pull incoming messages
// (coalesced 256B rows), residual+sigmoid, h@W1 partial, 16-lane shfl reduce,
// sigmoid, pool atomic (300k atomics total — negligible).
template <bool BF16>
__global__ __launch_bounds__(256) void gather_node_kernel(
    const void* __restrict__ msg, const int* __restrict__ pos,
    const int* __restrict__ eidx, const float* __restrict__ x,
    const int* __restrict__ batch,
    const float* __restrict__ W1, const float* __restrict__ b1,
    float* __restrict__ pool)
{
  const int t = threadIdx.x;
  const int n = blockIdx.x * 16 + (t >> 4);        // grid exact: NN/16
  const int i = t & 15;
  const int start = pos[n], end = pos[n + 1];

  float4 acc = make_float4(0.f, 0.f, 0.f, 0.f);
  if constexpr (!BF16) {
    const float4* m4 = (const float4*)msg;
    for (int p = start; p < end; ++p) {
      int e = eidx[p];
      float4 m = m4[(size_t)e * 16 + i];
      acc.x += m.x; acc.y += m.y; acc.z += m.z; acc.w += m.w;
    }
  } else {
    const unsigned short* mb = (const unsigned short*)msg;
    for (int p = start; p < end; ++p) {
      int e = eidx[p];
      ushort4 u = *(const ushort4*)(mb + (size_t)e * CC + 4 * i);
      acc.x += bf2f(u.x); acc.y += bf2f(u.y); acc.z += bf2f(u.z); acc.w += bf2f(u.w);
    }
  }

  const float4 xv = *(const float4*)(x + (size_t)n * CC + 4 * i);
  float h0 = sigmoidf_(xv.x + acc.x);
  float h1 = sigmoidf_(xv.y + acc.y);
  float h2 = sigmoidf_(xv.z + acc.z);
  float h3 = sigmoidf_(xv.w + acc.w);

  float o[6];
  const float* w = W1 + (size_t)(4 * i) * 6;
  #pragma unroll
  for (int j = 0; j < 6; ++j) {
    o[j] = h0 * w[j] + h1 * w[6 + j] + h2 * w[12 + j] + h3 * w[18 + j];
  }
  #pragma unroll
  for (int d = 8; d > 0; d >>= 1) {
    #pragma unroll
    for (int j = 0; j < 6; ++j) o[j] += __shfl_down(o[j], d, 16);
  }
  if (i == 0) {
    int g = batch[n];
    #pragma unroll
    for (int j = 0; j < 6; ++j)
      atomicAdd(&pool[g * 6 + j], sigmoidf_(o[j] + b1[j]));
  }
}

// Head: out[g] = relu(pool[g] @ W2 + b2)
__global__ void out_kernel(const float* __restrict__ pool,
                           const float* __restrict__ W2,
                           const float* __restrict__ b2,
                           float* __restrict__ out)
{
  int g = blockIdx.x * 64 + threadIdx.x;
  if (g < GG) {
    float acc = b2[0];
    #pragma unroll
    for (int j = 0; j < 6; ++j) acc = fmaf(pool[g * 6 + j], W2[j], acc);
    out[g] = fmaxf(acc, 0.f);
  }
}

static inline size_t al64(size_t v) { return (v + 63) & ~(size_t)63; }

extern "C" void kernel_launch(void* const* d_in, const int* in_sizes, int n_in,
                              void* d_out, int out_size, void* d_ws, size_t ws_size,
                              hipStream_t stream) {
  const float* x     = (const float*)d_in[0];
  const int*   ei    = (const int*)d_in[1];
  const float* ea    = (const float*)d_in[2];
  const int*   batch = (const int*)d_in[3];
  // d_in[4] = num_graphs scalar — fixed sizes
  const float* Wf = (const float*)d_in[5];
  const float* bf = (const float*)d_in[6];
  const float* Ws = (const float*)d_in[7];
  const float* bs = (const float*)d_in[8];
  const float* W1 = (const float*)d_in[9];
  const float* b1 = (const float*)d_in[10];
  const float* W2 = (const float*)d_in[11];
  const float* b2 = (const float*)d_in[12];
  float* out = (float*)d_out;

  // Workspace layout: msg | deg | pos | cursor | bsum | eidx | pool
  const size_t tail = al64((size_t)NN * 4) + al64((size_t)(NN + 1) * 4) +
                      al64((size_t)NN * 4) + al64(64 * 4) +
                      al64((size_t)EE * 4) + al64((size_t)GG * 6 * 4);
  const bool f32 = ws_size >= al64((size_t)EE * CC * 4) + tail;   // 208.3 MB

  char* p = (char*)d_ws;
  void* msg = (void*)p;
  p += al64(f32 ? (size_t)EE * CC * 4 : (size_t)EE * CC * 2);
  int* deg    = (int*)p; p += al64((size_t)NN * 4);
  int* pos    = (int*)p; p += al64((size_t)(NN + 1) * 4);
  int* cursor = (int*)p; p += al64((size_t)NN * 4);
  int* bsum   = (int*)p; p += al64(64 * 4);
  int* eidx   = (int*)p; p += al64((size_t)EE * 4);
  float* pool = (float*)p;

  hipMemsetAsync(deg, 0, (size_t)NN * 4, stream);
  hipMemsetAsync(pool, 0, (size_t)GG * 6 * 4, stream);

  // CSR build (by dst): 1.6M int atomics total vs 51.2M fp32 before.
  count_kernel<<<EE / 256, 256, 0, stream>>>(ei, deg);
  scan1_kernel<<<NSCAN, SCAN_B, 0, stream>>>(deg, pos, bsum);
  scan2_kernel<<<1, 64, 0, stream>>>(bsum);
  scan3_kernel<<<NSCAN, SCAN_B, 0, stream>>>(pos, bsum, cursor);
  fill_kernel<<<EE / 256, 256, 0, stream>>>(ei, cursor, eidx);

  if (f32) {
    edge_kernel<false><<<EE / EPB, 256, 0, stream>>>(x, ei, ea, Wf, bf, Ws, bs, msg);
    gather_node_kernel<false><<<NN / 16, 256, 0, stream>>>(msg, pos, eidx, x, batch, W1, b1, pool);
  } else {
    edge_kernel<true><<<EE / EPB, 256, 0, stream>>>(x, ei, ea, Wf, bf, Ws, bs, msg);
    gather_node_kernel<true><<<NN / 16, 256, 0, stream>>>(msg, pos, eidx, x, batch, W1, b1, pool);
  }
  out_kernel<<<(GG + 63) / 64, 64, 0, stream>>>(pool, W2, b2, out);
}

// Round 7
// 594.909 us; speedup vs baseline: 5.0370x; 1.4546x over previous
//
#include <hip/hip_runtime.h>
#include <hip/hip_bf16.h>
#include <stdint.h>

// Problem constants (PolyhedronModel CGConv): fixed sizes per reference.
#define NN 50000      // nodes
#define EE 800000     // edges
#define CC 64        // node channels
#define DE 32        // edge feature dim
#define KD 160       // 2*CC + DE
#define NC 128       // combined output cols: [Wf | Ws]
#define GG 512       // graphs
#define SCAN_B 1024
#define NSCAN ((NN + SCAN_B - 1) / SCAN_B)   // 49

typedef __attribute__((ext_vector_type(8))) short bf16x8;   // 8 bf16 (4 VGPR)
typedef __attribute__((ext_vector_type(4))) float f32x4;    // MFMA acc

__device__ __forceinline__ float sigmoidf_(float v) {
  return __fdividef(1.f, 1.f + __expf(-v));
}
// jax.nn.softplus(x) = max(x,0) + log1p(exp(-|x|))
__device__ __forceinline__ float softplusf_(float v) {
  return fmaxf(v, 0.f) + __logf(1.f + __expf(-fabsf(v)));
}
__device__ __forceinline__ unsigned short f2bf(float f) {   // RNE bf16 (msg path)
  uint32_t u = __float_as_uint(f);
  return (unsigned short)((u + 0x7FFFu + ((u >> 16) & 1u)) >> 16);
}
__device__ __forceinline__ float bf2f(unsigned short h) {
  return __uint_as_float(((uint32_t)h) << 16);
}
// Truncation split: f = hi + lo with lo captured exactly in f32, then truncated.
// Dropped lo*lo term => ~2^-16 relative product error. 2 ops + 2 shifts per elem.
__device__ __forceinline__ void tsplit(float f, short& hi, short& lo) {
  uint32_t u = __float_as_uint(f);
  float lf = f - __uint_as_float(u & 0xFFFF0000u);
  hi = (short)(u >> 16);
  lo = (short)(__float_as_uint(lf) >> 16);
}

// ---------------- CSR build (by dst) ----------------
__global__ void count_kernel(const int* __restrict__ ei, int* __restrict__ deg) {
  int e = blockIdx.x * 256 + threadIdx.x;          // grid exact: EE/256
  atomicAdd(&deg[ei[EE + e]], 1);                  // dst row
}

__global__ __launch_bounds__(SCAN_B) void scan1_kernel(
    const int* __restrict__ deg, int* __restrict__ pos, int* __restrict__ bsum) {
  __shared__ int s[SCAN_B];
  int t = threadIdx.x, i = blockIdx.x * SCAN_B + t;
  s[t] = (i < NN) ? deg[i] : 0;
  __syncthreads();
  for (int off = 1; off < SCAN_B; off <<= 1) {
    int a = (t >= off) ? s[t - off] : 0;
    __syncthreads();
    s[t] += a;
    __syncthreads();
  }
  if (i < NN) pos[i + 1] = s[t];
  if (t == SCAN_B - 1) bsum[blockIdx.x] = s[t];
}

__global__ void scan2_kernel(int* __restrict__ bsum) {
  __shared__ int s[64];
  int t = threadIdx.x;
  s[t] = (t < NSCAN) ? bsum[t] : 0;
  __syncthreads();
  for (int off = 1; off < 64; off <<= 1) {
    int a = (t >= off) ? s[t - off] : 0;
    __syncthreads();
    s[t] += a;
    __syncthreads();
  }
  bsum[t] = (t == 0) ? 0 : s[t - 1];
}

__global__ __launch_bounds__(SCAN_B) void scan3_kernel(
    int* __restrict__ pos, const int* __restrict__ bsum, int* __restrict__ cursor) {
  int t = threadIdx.x, i = blockIdx.x * SCAN_B + t;
  if (i < NN) {
    int v = pos[i + 1] + bsum[blockIdx.x];
    pos[i + 1] = v;
    if (i + 1 < NN) cursor[i + 1] = v;
  }
  if (i == 0) { pos[0] = 0; cursor[0] = 0; }
}

__global__ void fill_kernel(const int* __restrict__ ei,
                            int* __restrict__ cursor, int* __restrict__ eidx) {
  int e = blockIdx.x * 256 + threadIdx.x;
  int d = ei[EE + e];
  int slot = atomicAdd(&cursor[d], 1);
  eidx[slot] = e;
}

// ---------------- Prep: split x into bf16 hi/lo (removes per-kstep cvt cost) ----
__global__ void xsplit_kernel(const float* __restrict__ x,
                              unsigned short* __restrict__ xhi,
                              unsigned short* __restrict__ xlo) {
  int idx = blockIdx.x * 256 + threadIdx.x;        // grid exact: NN*CC/4/256 = 3125
  float4 v = ((const float4*)x)[idx];
  ushort4 h, l;
  short a, b;
  tsplit(v.x, a, b); h.x = (unsigned short)a; l.x = (unsigned short)b;
  tsplit(v.y, a, b); h.y = (unsigned short)a; l.y = (unsigned short)b;
  tsplit(v.z, a, b); h.z = (unsigned short)a; l.z = (unsigned short)b;
  tsplit(v.w, a, b); h.w = (unsigned short)a; l.w = (unsigned short)b;
  *(ushort4*)(xhi + (size_t)idx * 4) = h;
  *(ushort4*)(xlo + (size_t)idx * 4) = l;
}

// ---------------- Prep: pack W = [Wf|Ws] into B-fragment order, hi/lo ----------
// B frag for 16x16x32 MFMA: lane l supplies B[k=8*(l>>4)+i][n=l&15], i=0..7.
// Pack index p = ((s*8 + nt)*64 + l)*8 + i  (s = K-step, nt = 16-col tile).
__global__ void wprep_kernel(const float* __restrict__ Wf, const float* __restrict__ Ws,
                             short* __restrict__ Bph, short* __restrict__ Bpl) {
  int p = blockIdx.x * 256 + threadIdx.x;          // grid exact: 20480/256 = 80
  int i = p & 7, l = (p >> 3) & 63, tile = p >> 9; // tile = s*8 + nt, [0,40)
  int nt = tile & 7, s = tile >> 3;
  int k = s * 32 + 8 * (l >> 4) + i;
  int col = nt * 16 + (l & 15);
  float w = (col < CC) ? Wf[k * CC + col] : Ws[k * CC + (col - CC)];
  short hi, lo;
  tsplit(w, hi, lo);
  Bph[p] = hi;
  Bpl[p] = lo;
}

// ---------------- Edge kernel (MFMA bf16x3): msg = act(z @ [Wf|Ws]) ------------
// Block: 512 threads = 8 waves; 256 edges/block. Wave (mg=w>>1, ng=w&1):
//   4 m-tiles of 16 edges (mg picks the 64-edge group), n-tiles {2ng,2ng+1,2ng+4,2ng+5}
//   so each wave holds matching gate(F)/softplus(S) column pairs in-register.
// B (hi+lo, frag-packed) staged once into 80 KB LDS; A frags loaded from
// pre-split xhi/xlo (k-steps 0-3) or split on the fly from ea (k-step 4).
// K-chunks never straddle segment boundaries -> branch-free unrolled K-loop,
// no barriers after the single staging barrier.
template <bool BF16MSG>
__global__ __launch_bounds__(512) void edge_mfma_kernel(
    const unsigned short* __restrict__ xhi, const unsigned short* __restrict__ xlo,
    const int* __restrict__ ei, const float* __restrict__ ea,
    const short* __restrict__ Bph, const short* __restrict__ Bpl,
    const float* __restrict__ bfv, const float* __restrict__ bsv,
    void* __restrict__ msg)
{
  __shared__ short Bh[20480];   // 40960 B
  __shared__ short Bl[20480];   // 40960 B  -> 80 KiB total
  const int t = threadIdx.x;

  {  // stage packed weights: 5 x 512 float4 per component
    const float4* gh = (const float4*)Bph;
    const float4* gl = (const float4*)Bpl;
    float4* sh = (float4*)Bh;
    float4* sl = (float4*)Bl;
    #pragma unroll
    for (int r = 0; r < 5; ++r) {
      sh[r * 512 + t] = gh[r * 512 + t];
      sl[r * 512 + t] = gl[r * 512 + t];
    }
  }

  const int w  = t >> 6, l = t & 63;
  const int mg = w >> 1, ng = w & 1;
  const int ebase = blockIdx.x * 256 + mg * 64;
  const int lr = l & 15, lg = l >> 4;

  int e[4], dst[4], src[4];
  #pragma unroll
  for (int mt = 0; mt < 4; ++mt) {
    e[mt]   = ebase + mt * 16 + lr;
    dst[mt] = ei[EE + e[mt]];
    src[mt] = ei[e[mt]];
  }
  __syncthreads();

  f32x4 acc[4][4];   // [m-tile][q]; q: 0,1 = F cols (2ng,2ng+1), 2,3 = S cols (+4)
  #pragma unroll
  for (int mt = 0; mt < 4; ++mt)
    #pragma unroll
    for (int q = 0; q < 4; ++q) acc[mt][q] = (f32x4){0.f, 0.f, 0.f, 0.f};

  #pragma unroll
  for (int s = 0; s < 5; ++s) {
    // ---- A fragments (hi/lo) ----
    bf16x8 ah[4], al[4];
    if (s < 4) {
      const int koff = (s & 1) * 32 + 8 * lg;      // within-row k offset
      #pragma unroll
      for (int mt = 0; mt < 4; ++mt) {
        const int row = (s < 2) ? dst[mt] : src[mt];
        const size_t o = (size_t)row * CC + koff;
        ah[mt] = *(const bf16x8*)(xhi + o);
        al[mt] = *(const bf16x8*)(xlo + o);
      }
    } else {
      #pragma unroll
      for (int mt = 0; mt < 4; ++mt) {
        const float4* p4 = (const float4*)(ea + (size_t)e[mt] * DE + 8 * lg);
        float4 v0 = p4[0], v1 = p4[1];
        float v[8] = {v0.x, v0.y, v0.z, v0.w, v1.x, v1.y, v1.z, v1.w};
        #pragma unroll
        for (int i = 0; i < 8; ++i) {
          short hh, ll;
          tsplit(v[i], hh, ll);
          ah[mt][i] = hh;
          al[mt][i] = ll;
        }
      }
    }
    // ---- B fragments (hi/lo) from LDS ----
    bf16x8 bh[4], bl[4];
    #pragma unroll
    for (int q = 0; q < 4; ++q) {
      const int nt  = 2 * ng + (q & 1) + (q >> 1) * 4;
      const int off = ((s * 8 + nt) * 64 + l) * 8;
      bh[q] = *(const bf16x8*)(Bh + off);
      bl[q] = *(const bf16x8*)(Bl + off);
    }
    // ---- 3-product compensated MFMA, interleaved for independence ----
    #pragma unroll
    for (int mt = 0; mt < 4; ++mt)
      #pragma unroll
      for (int q = 0; q < 4; ++q)
        acc[mt][q] = __builtin_amdgcn_mfma_f32_16x16x32_bf16(ah[mt], bh[q], acc[mt][q], 0, 0, 0);
    #pragma unroll
    for (int mt = 0; mt < 4; ++mt)
      #pragma unroll
      for (int q = 0; q < 4; ++q)
        acc[mt][q] = __builtin_amdgcn_mfma_f32_16x16x32_bf16(al[mt], bh[q], acc[mt][q], 0, 0, 0);
    #pragma unroll
    for (int mt = 0; mt < 4; ++mt)
      #pragma unroll
      for (int q = 0; q < 4; ++q)
        acc[mt][q] = __builtin_amdgcn_mfma_f32_16x16x32_bf16(ah[mt], bl[q], acc[mt][q], 0, 0, 0);
  }

  // ---- epilogue: bias + sigmoid*softplus, store msg rows ----
  // C/D layout (verified, guide §3): col = lane&15, row = (lane>>4)*4 + reg.
  #pragma unroll
  for (int p2 = 0; p2 < 2; ++p2) {
    const int ch = (2 * ng + p2) * 16 + lr;
    const float bF = bfv[ch], bS = bsv[ch];
    #pragma unroll
    for (int mt = 0; mt < 4; ++mt) {
      f32x4 F = acc[mt][p2];
      f32x4 S = acc[mt][p2 + 2];
      #pragma unroll
      for (int r = 0; r < 4; ++r) {
        const int edge = ebase + mt * 16 + lg * 4 + r;
        const float mval = sigmoidf_(F[r] + bF) * softplusf_(S[r] + bS);
        if constexpr (!BF16MSG) {
          ((float*)msg)[(size_t)edge * CC + ch] = mval;
        } else {
          ((unsigned short*)msg)[(size_t)edge * CC + ch] = f2bf(mval);
        }
      }
    }
  }
}

// ---------------- Fused gather + node head ----------------
template <bool BF16MSG>
__global__ __launch_bounds__(256) void gather_node_kernel(
    const void* __restrict__ msg, const int* __restrict__ pos,
    const int* __restrict__ eidx, const float* __restrict__ x,
    const int* __restrict__ batch,
    const float* __restrict__ W1, const float* __restrict__ b1,
    float* __restrict__ pool)
{
  const int t = threadIdx.x;
  const int n = blockIdx.x * 16 + (t >> 4);        // grid exact: NN/16
  const int i = t & 15;
  const int start = pos[n], end = pos[n + 1];

  float4 acc = make_float4(0.f, 0.f, 0.f, 0.f);
  if constexpr (!BF16MSG) {
    const float4* m4 = (const float4*)msg;
    for (int p = start; p < end; ++p) {
      int e = eidx[p];
      float4 m = m4[(size_t)e * 16 + i];
      acc.x += m.x; acc.y += m.y; acc.z += m.z; acc.w += m.w;
    }
  } else {
    const unsigned short* mb = (const unsigned short*)msg;
    for (int p = start; p < end; ++p) {
      int e = eidx[p];
      ushort4 u = *(const ushort4*)(mb + (size_t)e * CC + 4 * i);
      acc.x += bf2f(u.x); acc.y += bf2f(u.y); acc.z += bf2f(u.z); acc.w += bf2f(u.w);
    }
  }

  const float4 xv = *(const float4*)(x + (size_t)n * CC + 4 * i);
  float h0 = sigmoidf_(xv.x + acc.x);
  float h1 = sigmoidf_(xv.y + acc.y);
  float h2 = sigmoidf_(xv.z + acc.z);
  float h3 = sigmoidf_(xv.w + acc.w);

  float o[6];
  const float* wp = W1 + (size_t)(4 * i) * 6;
  #pragma unroll
  for (int j = 0; j < 6; ++j) {
    o[j] = h0 * wp[j] + h1 * wp[6 + j] + h2 * wp[12 + j] + h3 * wp[18 + j];
  }
  #pragma unroll
  for (int d = 8; d > 0; d >>= 1) {
    #pragma unroll
    for (int j = 0; j < 6; ++j) o[j] += __shfl_down(o[j], d, 16);
  }
  if (i == 0) {
    int g = batch[n];
    #pragma unroll
    for (int j = 0; j < 6; ++j)
      atomicAdd(&pool[g * 6 + j], sigmoidf_(o[j] + b1[j]));
  }
}

// Head: out[g] = relu(pool[g] @ W2 + b2)
__global__ void out_kernel(const float* __restrict__ pool,
                           const float* __restrict__ W2,
                           const float* __restrict__ b2,
                           float* __restrict__ out)
{
  int g = blockIdx.x * 64 + threadIdx.x;
  if (g < GG) {
    float acc = b2[0];
    #pragma unroll
    for (int j = 0; j < 6; ++j) acc = fmaf(pool[g * 6 + j], W2[j], acc);
    out[g] = fmaxf(acc, 0.f);
  }
}

static inline size_t al64(size_t v) { return (v + 63) & ~(size_t)63; }

extern "C" void kernel_launch(void* const* d_in, const int* in_sizes, int n_in,
                              void* d_out, int out_size, void* d_ws, size_t ws_size,
                              hipStream_t stream) {
  const float* x     = (const float*)d_in[0];
  const int*   ei    = (const int*)d_in[1];
  const float* ea    = (const float*)d_in[2];
  const int*   batch = (const int*)d_in[3];
  // d_in[4] = num_graphs scalar — fixed sizes
  const float* Wf = (const float*)d_in[5];
  const float* bf = (const float*)d_in[6];
  const float* Ws = (const float*)d_in[7];
  const float* bs = (const float*)d_in[8];
  const float* W1 = (const float*)d_in[9];
  const float* b1 = (const float*)d_in[10];
  const float* W2 = (const float*)d_in[11];
  const float* b2 = (const float*)d_in[12];
  float* out = (float*)d_out;

  // Workspace: msg | xhi | xlo | Bph | Bpl | deg | pos | cursor | bsum | eidx | pool
  const size_t fixed = al64((size_t)NN * CC * 2) * 2 +          // xhi, xlo
                       al64((size_t)KD * NC * 2) * 2 +          // Bph, Bpl
                       al64((size_t)NN * 4) + al64((size_t)(NN + 1) * 4) +
                       al64((size_t)NN * 4) + al64(64 * 4) +
                       al64((size_t)EE * 4) + al64((size_t)GG * 6 * 4);
  const bool f32 = ws_size >= al64((size_t)EE * CC * 4) + fixed;

  char* p = (char*)d_ws;
  void* msg = (void*)p;
  p += al64(f32 ? (size_t)EE * CC * 4 : (size_t)EE * CC * 2);
  unsigned short* xhi = (unsigned short*)p; p += al64((size_t)NN * CC * 2);
  unsigned short* xlo = (unsigned short*)p; p += al64((size_t)NN * CC * 2);
  short* Bph = (short*)p; p += al64((size_t)KD * NC * 2);
  short* Bpl = (short*)p; p += al64((size_t)KD * NC * 2);
  int* deg    = (int*)p; p += al64((size_t)NN * 4);
  int* pos    = (int*)p; p += al64((size_t)(NN + 1) * 4);
  int* cursor = (int*)p; p += al64((size_t)NN * 4);
  int* bsum   = (int*)p; p += al64(64 * 4);
  int* eidx   = (int*)p; p += al64((size_t)EE * 4);
  float* pool = (float*)p;

  hipMemsetAsync(deg, 0, (size_t)NN * 4, stream);
  hipMemsetAsync(pool, 0, (size_t)GG * 6 * 4, stream);

  // Prep for the MFMA edge kernel (idempotent; re-run every call).
  xsplit_kernel<<<NN * CC / 4 / 256, 256, 0, stream>>>(x, xhi, xlo);   // 3125 blocks
  wprep_kernel<<<KD * NC / 256, 256, 0, stream>>>(Wf, Ws, Bph, Bpl);   // 80 blocks

  // CSR build (by dst).
  count_kernel<<<EE / 256, 256, 0, stream>>>(ei, deg);
  scan1_kernel<<<NSCAN, SCAN_B, 0, stream>>>(deg, pos, bsum);
  scan2_kernel<<<1, 64, 0, stream>>>(bsum);
  scan3_kernel<<<NSCAN, SCAN_B, 0, stream>>>(pos, bsum, cursor);
  fill_kernel<<<EE / 256, 256, 0, stream>>>(ei, cursor, eidx);

  if (f32) {
    edge_mfma_kernel<false><<<EE / 256, 512, 0, stream>>>(xhi, xlo, ei, ea, Bph, Bpl, bf, bs, msg);
    gather_node_kernel<false><<<NN / 16, 256, 0, stream>>>(msg, pos, eidx, x, batch, W1, b1, pool);
  } else {
    edge_mfma_kernel<true><<<EE / 256, 512, 0, stream>>>(xhi, xlo, ei, ea, Bph, Bpl, bf, bs, msg);
    gather_node_kernel<true><<<NN / 16, 256, 0, stream>>>(msg, pos, eidx, x, batch, W1, b1, pool);
  }
  out_kernel<<<(GG + 63) / 64, 64, 0, stream>>>(pool, W2, b2, out);
}

// Round 8
// 561.171 us; speedup vs baseline: 5.3398x; 1.0601x over previous
//
#include <hip/hip_runtime.h>
#include <hip/hip_bf16.h>
#include <stdint.h>

// Problem constants (PolyhedronModel CGConv): fixed sizes per reference.
#define NN 50000      // nodes
#define EE 800000     // edges
#define CC 64        // node channels
#define DE 32        // edge feature dim
#define KD 160       // 2*CC + DE
#define NC 128       // combined output cols: [Wf | Ws]
#define GG 512       // graphs
#define SCAN_B 1024
#define NSCAN ((NN + SCAN_B - 1) / SCAN_B)   // 49

typedef __attribute__((ext_vector_type(8))) short bf16x8;   // 8 bf16 (4 VGPR)
typedef __attribute__((ext_vector_type(4))) float f32x4;    // MFMA acc

__device__ __forceinline__ float sigmoidf_(float v) {
  return __fdividef(1.f, 1.f + __expf(-v));
}
// jax.nn.softplus(x) = max(x,0) + log1p(exp(-|x|))
__device__ __forceinline__ float softplusf_(float v) {
  return fmaxf(v, 0.f) + __logf(1.f + __expf(-fabsf(v)));
}
__device__ __forceinline__ unsigned short f2bf(float f) {   // RNE bf16 (msg path)
  uint32_t u = __float_as_uint(f);
  return (unsigned short)((u + 0x7FFFu + ((u >> 16) & 1u)) >> 16);
}
__device__ __forceinline__ float bf2f(unsigned short h) {
  return __uint_as_float(((uint32_t)h) << 16);
}
// Truncation split: f = hi + lo with lo captured exactly in f32, then truncated.
// Dropped lo*lo term => ~2^-16 relative product error.
__device__ __forceinline__ void tsplit(float f, short& hi, short& lo) {
  uint32_t u = __float_as_uint(f);
  float lf = f - __uint_as_float(u & 0xFFFF0000u);
  hi = (short)(u >> 16);
  lo = (short)(__float_as_uint(lf) >> 16);
}

// ---------------- CSR build (by dst) ----------------
__global__ void count_kernel(const int* __restrict__ ei, int* __restrict__ deg) {
  int e = blockIdx.x * 256 + threadIdx.x;          // grid exact: EE/256
  atomicAdd(&deg[ei[EE + e]], 1);                  // dst row
}

__global__ __launch_bounds__(SCAN_B) void scan1_kernel(
    const int* __restrict__ deg, int* __restrict__ pos, int* __restrict__ bsum) {
  __shared__ int s[SCAN_B];
  int t = threadIdx.x, i = blockIdx.x * SCAN_B + t;
  s[t] = (i < NN) ? deg[i] : 0;
  __syncthreads();
  for (int off = 1; off < SCAN_B; off <<= 1) {
    int a = (t >= off) ? s[t - off] : 0;
    __syncthreads();
    s[t] += a;
    __syncthreads();
  }
  if (i < NN) pos[i + 1] = s[t];
  if (t == SCAN_B - 1) bsum[blockIdx.x] = s[t];
}

__global__ void scan2_kernel(int* __restrict__ bsum) {
  __shared__ int s[64];
  int t = threadIdx.x;
  s[t] = (t < NSCAN) ? bsum[t] : 0;
  __syncthreads();
  for (int off = 1; off < 64; off <<= 1) {
    int a = (t >= off) ? s[t - off] : 0;
    __syncthreads();
    s[t] += a;
    __syncthreads();
  }
  bsum[t] = (t == 0) ? 0 : s[t - 1];
}

__global__ __launch_bounds__(SCAN_B) void scan3_kernel(
    int* __restrict__ pos, const int* __restrict__ bsum, int* __restrict__ cursor) {
  int t = threadIdx.x, i = blockIdx.x * SCAN_B + t;
  if (i < NN) {
    int v = pos[i + 1] + bsum[blockIdx.x];
    pos[i + 1] = v;
    if (i + 1 < NN) cursor[i + 1] = v;
  }
  if (i == 0) { pos[0] = 0; cursor[0] = 0; }
}

// fill also emits slot-ordered dst/src so the edge kernel reads them coalesced.
__global__ void fill_kernel(const int* __restrict__ ei, int* __restrict__ cursor,
                            int* __restrict__ eidx, int* __restrict__ dsts,
                            int* __restrict__ srcs) {
  int e = blockIdx.x * 256 + threadIdx.x;
  int d = ei[EE + e];
  int s = ei[e];
  int slot = atomicAdd(&cursor[d], 1);
  eidx[slot] = e;
  dsts[slot] = d;
  srcs[slot] = s;
}

// ---------------- Prep: split x into bf16 hi/lo ----------------
__global__ void xsplit_kernel(const float* __restrict__ x,
                              unsigned short* __restrict__ xhi,
                              unsigned short* __restrict__ xlo) {
  int idx = blockIdx.x * 256 + threadIdx.x;        // grid exact: NN*CC/4/256 = 3125
  float4 v = ((const float4*)x)[idx];
  ushort4 h, l;
  short a, b;
  tsplit(v.x, a, b); h.x = (unsigned short)a; l.x = (unsigned short)b;
  tsplit(v.y, a, b); h.y = (unsigned short)a; l.y = (unsigned short)b;
  tsplit(v.z, a, b); h.z = (unsigned short)a; l.z = (unsigned short)b;
  tsplit(v.w, a, b); h.w = (unsigned short)a; l.w = (unsigned short)b;
  *(ushort4*)(xhi + (size_t)idx * 4) = h;
  *(ushort4*)(xlo + (size_t)idx * 4) = l;
}

// ---------------- Prep: pack W = [Wf|Ws] into B-fragment order, hi/lo ----------
// B frag for 16x16x32 MFMA: lane l supplies B[k=8*(l>>4)+i][n=l&15], i=0..7.
// Pack index p = ((s*8 + nt)*64 + l)*8 + i  (s = K-step, nt = 16-col tile).
__global__ void wprep_kernel(const float* __restrict__ Wf, const float* __restrict__ Ws,
                             short* __restrict__ Bph, short* __restrict__ Bpl) {
  int p = blockIdx.x * 256 + threadIdx.x;          // grid exact: 20480/256 = 80
  int i = p & 7, l = (p >> 3) & 63, tile = p >> 9; // tile = s*8 + nt, [0,40)
  int nt = tile & 7, s = tile >> 3;
  int k = s * 32 + 8 * (l >> 4) + i;
  int col = nt * 16 + (l & 15);
  float w = (col < CC) ? Wf[k * CC + col] : Ws[k * CC + (col - CC)];
  short hi, lo;
  tsplit(w, hi, lo);
  Bph[p] = hi;
  Bpl[p] = lo;
}

// ---------------- Edge kernel (MFMA bf16x3), dst-sorted slot order ------------
// Processes SLOTS (dst-sorted CSR positions); reads edge data via eidx/dsts/srcs
// (all slot-coalesced) and writes msg[slot] so the gather is a contiguous
// segmented reduction. Bh (40 KB) staged in LDS -> 2 blocks/CU (was 80 KB -> 1);
// Bl read from global (L1/L2-resident, coalesced 1KB/wave per fragment).
template <bool BF16MSG>
__global__ __launch_bounds__(512) void edge_mfma_kernel(
    const unsigned short* __restrict__ xhi, const unsigned short* __restrict__ xlo,
    const int* __restrict__ eidx, const int* __restrict__ dsts,
    const int* __restrict__ srcs, const float* __restrict__ ea,
    const short* __restrict__ Bph, const short* __restrict__ Bpl,
    const float* __restrict__ bfv, const float* __restrict__ bsv,
    void* __restrict__ msg)
{
  __shared__ short Bh[20480];   // 40 KiB only (Bl stays in global)
  const int t = threadIdx.x;

  {  // stage packed hi weights: 5 x 512 float4
    const float4* gh = (const float4*)Bph;
    float4* sh = (float4*)Bh;
    #pragma unroll
    for (int r = 0; r < 5; ++r) sh[r * 512 + t] = gh[r * 512 + t];
  }

  const int w  = t >> 6, l = t & 63;
  const int mg = w >> 1, ng = w & 1;
  const int sbase = blockIdx.x * 256 + mg * 64;    // slot base for this wave
  const int lr = l & 15, lg = l >> 4;

  int dst[4], src[4], ep[4];
  #pragma unroll
  for (int mt = 0; mt < 4; ++mt) {
    const int slot = sbase + mt * 16 + lr;
    dst[mt] = dsts[slot];                          // coalesced; near-constant per tile
    src[mt] = srcs[slot];
    ep[mt]  = eidx[slot];                          // original edge id (for ea row)
  }
  __syncthreads();

  f32x4 acc[4][4];   // [m-tile][q]; q: 0,1 = F cols (2ng,2ng+1), 2,3 = S cols (+4)
  #pragma unroll
  for (int mt = 0; mt < 4; ++mt)
    #pragma unroll
    for (int q = 0; q < 4; ++q) acc[mt][q] = (f32x4){0.f, 0.f, 0.f, 0.f};

  const bf16x8* Blg = (const bf16x8*)Bpl;

  #pragma unroll
  for (int s = 0; s < 5; ++s) {
    // ---- A fragments (hi/lo) ----
    bf16x8 ah[4], al[4];
    if (s < 4) {
      const int koff = (s & 1) * 32 + 8 * lg;      // within-row k offset
      #pragma unroll
      for (int mt = 0; mt < 4; ++mt) {
        const int row = (s < 2) ? dst[mt] : src[mt];
        const size_t o = (size_t)row * CC + koff;
        ah[mt] = *(const bf16x8*)(xhi + o);
        al[mt] = *(const bf16x8*)(xlo + o);
      }
    } else {
      #pragma unroll
      for (int mt = 0; mt < 4; ++mt) {
        const float4* p4 = (const float4*)(ea + (size_t)ep[mt] * DE + 8 * lg);
        float4 v0 = p4[0], v1 = p4[1];
        float v[8] = {v0.x, v0.y, v0.z, v0.w, v1.x, v1.y, v1.z, v1.w};
        #pragma unroll
        for (int i = 0; i < 8; ++i) {
          short hh, ll;
          tsplit(v[i], hh, ll);
          ah[mt][i] = hh;
          al[mt][i] = ll;
        }
      }
    }
    // ---- B fragments: hi from LDS, lo from global ----
    bf16x8 bh[4], bl[4];
    #pragma unroll
    for (int q = 0; q < 4; ++q) {
      const int nt  = 2 * ng + (q & 1) + (q >> 1) * 4;
      bh[q] = *(const bf16x8*)(Bh + ((s * 8 + nt) * 64 + l) * 8);
      bl[q] = Blg[(s * 8 + nt) * 64 + l];
    }
    // ---- 3-product compensated MFMA ----
    #pragma unroll
    for (int mt = 0; mt < 4; ++mt)
      #pragma unroll
      for (int q = 0; q < 4; ++q)
        acc[mt][q] = __builtin_amdgcn_mfma_f32_16x16x32_bf16(ah[mt], bh[q], acc[mt][q], 0, 0, 0);
    #pragma unroll
    for (int mt = 0; mt < 4; ++mt)
      #pragma unroll
      for (int q = 0; q < 4; ++q)
        acc[mt][q] = __builtin_amdgcn_mfma_f32_16x16x32_bf16(al[mt], bh[q], acc[mt][q], 0, 0, 0);
    #pragma unroll
    for (int mt = 0; mt < 4; ++mt)
      #pragma unroll
      for (int q = 0; q < 4; ++q)
        acc[mt][q] = __builtin_amdgcn_mfma_f32_16x16x32_bf16(ah[mt], bl[q], acc[mt][q], 0, 0, 0);
  }

  // ---- epilogue: bias + sigmoid*softplus, store msg at SLOT rows ----
  // C/D layout (verified): col = lane&15, row = (lane>>4)*4 + reg.
  #pragma unroll
  for (int p2 = 0; p2 < 2; ++p2) {
    const int ch = (2 * ng + p2) * 16 + lr;
    const float bF = bfv[ch], bS = bsv[ch];
    #pragma unroll
    for (int mt = 0; mt < 4; ++mt) {
      f32x4 F = acc[mt][p2];
      f32x4 S = acc[mt][p2 + 2];
      #pragma unroll
      for (int r = 0; r < 4; ++r) {
        const int oslot = sbase + mt * 16 + lg * 4 + r;
        const float mval = sigmoidf_(F[r] + bF) * softplusf_(S[r] + bS);
        if constexpr (!BF16MSG) {
          ((float*)msg)[(size_t)oslot * CC + ch] = mval;
        } else {
          ((unsigned short*)msg)[(size_t)oslot * CC + ch] = f2bf(mval);
        }
      }
    }
  }
}

// ---------------- Fused gather + node head: CONTIGUOUS segmented reduce -------
// msg is slot-ordered (dst-sorted), so node n owns rows [pos[n], pos[n+1]) —
// a pure streaming read, no eidx indirection.
template <bool BF16MSG>
__global__ __launch_bounds__(256) void gather_node_kernel(
    const void* __restrict__ msg, const int* __restrict__ pos,
    const float* __restrict__ x, const int* __restrict__ batch,
    const float* __restrict__ W1, const float* __restrict__ b1,
    float* __restrict__ pool)
{
  const int t = threadIdx.x;
  const int n = blockIdx.x * 16 + (t >> 4);        // grid exact: NN/16
  const int i = t & 15;
  const int start = pos[n], end = pos[n + 1];

  float4 acc = make_float4(0.f, 0.f, 0.f, 0.f);
  if constexpr (!BF16MSG) {
    const float4* m4 = (const float4*)msg;
    for (int p = start; p < end; ++p) {
      float4 m = m4[(size_t)p * 16 + i];
      acc.x += m.x; acc.y += m.y; acc.z += m.z; acc.w += m.w;
    }
  } else {
    const unsigned short* mb = (const unsigned short*)msg;
    for (int p = start; p < end; ++p) {
      ushort4 u = *(const ushort4*)(mb + (size_t)p * CC + 4 * i);
      acc.x += bf2f(u.x); acc.y += bf2f(u.y); acc.z += bf2f(u.z); acc.w += bf2f(u.w);
    }
  }

  const float4 xv = *(const float4*)(x + (size_t)n * CC + 4 * i);
  float h0 = sigmoidf_(xv.x + acc.x);
  float h1 = sigmoidf_(xv.y + acc.y);
  float h2 = sigmoidf_(xv.z + acc.z);
  float h3 = sigmoidf_(xv.w + acc.w);

  float o[6];
  const float* wp = W1 + (size_t)(4 * i) * 6;
  #pragma unroll
  for (int j = 0; j < 6; ++j) {
    o[j] = h0 * wp[j] + h1 * wp[6 + j] + h2 * wp[12 + j] + h3 * wp[18 + j];
  }
  #pragma unroll
  for (int d = 8; d > 0; d >>= 1) {
    #pragma unroll
    for (int j = 0; j < 6; ++j) o[j] += __shfl_down(o[j], d, 16);
  }
  if (i == 0) {
    int g = batch[n];
    #pragma unroll
    for (int j = 0; j < 6; ++j)
      atomicAdd(&pool[g * 6 + j], sigmoidf_(o[j] + b1[j]));
  }
}

// Head: out[g] = relu(pool[g] @ W2 + b2)
__global__ void out_kernel(const float* __restrict__ pool,
                           const float* __restrict__ W2,
                           const float* __restrict__ b2,
                           float* __restrict__ out)
{
  int g = blockIdx.x * 64 + threadIdx.x;
  if (g < GG) {
    float acc = b2[0];
    #pragma unroll
    for (int j = 0; j < 6; ++j) acc = fmaf(pool[g * 6 + j], W2[j], acc);
    out[g] = fmaxf(acc, 0.f);
  }
}

static inline size_t al64(size_t v) { return (v + 63) & ~(size_t)63; }

extern "C" void kernel_launch(void* const* d_in, const int* in_sizes, int n_in,
                              void* d_out, int out_size, void* d_ws, size_t ws_size,
                              hipStream_t stream) {
  const float* x     = (const float*)d_in[0];
  const int*   ei    = (const int*)d_in[1];
  const float* ea    = (const float*)d_in[2];
  const int*   batch = (const int*)d_in[3];
  // d_in[4] = num_graphs scalar — fixed sizes
  const float* Wf = (const float*)d_in[5];
  const float* bf = (const float*)d_in[6];
  const float* Ws = (const float*)d_in[7];
  const float* bs = (const float*)d_in[8];
  const float* W1 = (const float*)d_in[9];
  const float* b1 = (const float*)d_in[10];
  const float* W2 = (const float*)d_in[11];
  const float* b2 = (const float*)d_in[12];
  float* out = (float*)d_out;

  // Workspace: msg | xhi | xlo | Bph | Bpl | deg | pos | cursor | bsum
  //            | eidx | dsts | srcs | pool
  const size_t fixed = al64((size_t)NN * CC * 2) * 2 +          // xhi, xlo
                       al64((size_t)KD * NC * 2) * 2 +          // Bph, Bpl
                       al64((size_t)NN * 4) + al64((size_t)(NN + 1) * 4) +
                       al64((size_t)NN * 4) + al64(64 * 4) +
                       al64((size_t)EE * 4) * 3 +               // eidx, dsts, srcs
                       al64((size_t)GG * 6 * 4);
  const bool f32 = ws_size >= al64((size_t)EE * CC * 4) + fixed;

  char* p = (char*)d_ws;
  void* msg = (void*)p;
  p += al64(f32 ? (size_t)EE * CC * 4 : (size_t)EE * CC * 2);
  unsigned short* xhi = (unsigned short*)p; p += al64((size_t)NN * CC * 2);
  unsigned short* xlo = (unsigned short*)p; p += al64((size_t)NN * CC * 2);
  short* Bph = (short*)p; p += al64((size_t)KD * NC * 2);
  short* Bpl = (short*)p; p += al64((size_t)KD * NC * 2);
  int* deg    = (int*)p; p += al64((size_t)NN * 4);
  int* pos    = (int*)p; p += al64((size_t)(NN + 1) * 4);
  int* cursor = (int*)p; p += al64((size_t)NN * 4);
  int* bsum   = (int*)p; p += al64(64 * 4);
  int* eidx   = (int*)p; p += al64((size_t)EE * 4);
  int* dsts   = (int*)p; p += al64((size_t)EE * 4);
  int* srcs   = (int*)p; p += al64((size_t)EE * 4);
  float* pool = (float*)p;

  hipMemsetAsync(deg, 0, (size_t)NN * 4, stream);
  hipMemsetAsync(pool, 0, (size_t)GG * 6 * 4, stream);

  // Prep for the MFMA edge kernel (idempotent; re-run every call).
  xsplit_kernel<<<NN * CC / 4 / 256, 256, 0, stream>>>(x, xhi, xlo);   // 3125 blocks
  wprep_kernel<<<KD * NC / 256, 256, 0, stream>>>(Wf, Ws, Bph, Bpl);   // 80 blocks

  // CSR build (by dst).
  count_kernel<<<EE / 256, 256, 0, stream>>>(ei, deg);
  scan1_kernel<<<NSCAN, SCAN_B, 0, stream>>>(deg, pos, bsum);
  scan2_kernel<<<1, 64, 0, stream>>>(bsum);
  scan3_kernel<<<NSCAN, SCAN_B, 0, stream>>>(pos, bsum, cursor);
  fill_kernel<<<EE / 256, 256, 0, stream>>>(ei, cursor, eidx, dsts, srcs);

  if (f32) {
    edge_mfma_kernel<false><<<EE / 256, 512, 0, stream>>>(xhi, xlo, eidx, dsts, srcs, ea, Bph, Bpl, bf, bs, msg);
    gather_node_kernel<false><<<NN / 16, 256, 0, stream>>>(msg, pos, x, batch, W1, b1, pool);
  } else {
    edge_mfma_kernel<true><<<EE / 256, 512, 0, stream>>>(xhi, xlo, eidx, dsts, srcs, ea, Bph, Bpl, bf, bs, msg);
    gather_node_kernel<true><<<NN / 16, 256, 0, stream>>>(msg, pos, x, batch, W1, b1, pool);
  }
  out_kernel<<<(GG + 63) / 64, 64, 0, stream>>>(pool, W2, b2, out);
}